// Round 8
// baseline (242.802 us; speedup 1.0000x reference)
//
#include <hip/hip_runtime.h>

typedef unsigned short ushort_t;
typedef __bf16 bf16x8 __attribute__((ext_vector_type(8)));
typedef float floatx4 __attribute__((ext_vector_type(4)));

__device__ inline ushort_t f2bf(float f) {
    __bf16 h = (__bf16)f;
    return __builtin_bit_cast(ushort_t, h);
}

// ---------------------------------------------------------------- prep: wt transpose (blocks 0..2303) + cast x (blocks 2304..8447)
__global__ __launch_bounds__(256) void prep_kernel(
    const float* __restrict__ x, ushort_t* __restrict__ xbf,
    const float* __restrict__ W0, const float* __restrict__ W1,
    const float* __restrict__ W2, const float* __restrict__ W3,
    ushort_t* __restrict__ T0, ushort_t* __restrict__ T1,
    ushort_t* __restrict__ T2, ushort_t* __restrict__ T3) {
    int bx = blockIdx.x;
    int tid = threadIdx.x;
    if (bx < 2304) {
        __shared__ float t[32][33];
        int w = bx / 576, rem = bx % 576;
        const float* W; ushort_t* T;
        switch (w) {
            case 0: W = W0; T = T0; break;
            case 1: W = W1; T = T1; break;
            case 2: W = W2; T = T2; break;
            default: W = W3; T = T3; break;
        }
        int n0 = (rem / 24) * 32, k0 = (rem % 24) * 32;
        int tx = tid & 31, ty = tid >> 5;   // 32 x 8
        for (int i = 0; i < 4; ++i)
            t[ty + i * 8][tx] = W[(k0 + ty + i * 8) * 768 + n0 + tx];
        __syncthreads();
        for (int i = 0; i < 4; ++i)
            T[(n0 + ty + i * 8) * 768 + k0 + tx] = f2bf(t[tx][ty + i * 8]);
    } else {
        int i = ((bx - 2304) * 256 + tid) * 4;
        float4 v = *(const float4*)(x + i);
        ushort4 u;
        u.x = f2bf(v.x); u.y = f2bf(v.y); u.z = f2bf(v.z); u.w = f2bf(v.w);
        *(ushort4*)(xbf + i) = u;
    }
}

// ---------------------------------------------------------------- fused QKV GEMM (dbuf reg-prefetch, 1 barrier/iter)
// Q is pre-scaled by 0.125 * log2(e) so attention can use native exp2.
__global__ __launch_bounds__(256) void gemm_qkv(
    const ushort_t* __restrict__ A,
    const ushort_t* __restrict__ Tq, const ushort_t* __restrict__ Tk, const ushort_t* __restrict__ Tv,
    const float* __restrict__ bq, const float* __restrict__ bk, const float* __restrict__ bv,
    ushort_t* __restrict__ Qb, ushort_t* __restrict__ Kb, ushort_t* __restrict__ Vtb) {
    __shared__ ushort_t As[2][128 * 72];
    __shared__ ushort_t Bs[2][128 * 72];
    int tid = threadIdx.x;
    int m0 = blockIdx.x * 128;
    int nt = blockIdx.y;       // 0..17
    int which = nt / 6;
    int n0 = (nt % 6) * 128;
    const ushort_t* Bt = which == 0 ? Tq : (which == 1 ? Tk : Tv);
    const float* bias = which == 0 ? bq : (which == 1 ? bk : bv);

    int wave = tid >> 6;
    int ln = tid & 15;
    int quad = (tid >> 4) & 3;
    int wm = (wave & 1) * 64;
    int wn = (wave >> 1) * 64;

    floatx4 acc[4][4];
    floatx4 z = {0.f, 0.f, 0.f, 0.f};
    for (int i = 0; i < 4; ++i)
        for (int j = 0; j < 4; ++j) acc[i][j] = z;

    int srow = tid >> 3;          // 0..31
    int scol = (tid & 7) * 8;     // 0,8,...,56

    uint4 ar[4], br[4];
    // prologue: tile 0 -> regs -> buf0
    for (int p = 0; p < 4; ++p) {
        int r = p * 32 + srow;
        ar[p] = *(const uint4*)&A[(m0 + r) * 768 + scol];
        br[p] = *(const uint4*)&Bt[(n0 + r) * 768 + scol];
    }
    for (int p = 0; p < 4; ++p) {
        int r = p * 32 + srow;
        *(uint4*)&As[0][r * 72 + scol] = ar[p];
        *(uint4*)&Bs[0][r * 72 + scol] = br[p];
    }
    __syncthreads();

    for (int kt = 0; kt < 12; ++kt) {
        int cur = kt & 1;
        if (kt < 11) {
            int k0 = (kt + 1) * 64;
            for (int p = 0; p < 4; ++p) {
                int r = p * 32 + srow;
                ar[p] = *(const uint4*)&A[(m0 + r) * 768 + k0 + scol];
                br[p] = *(const uint4*)&Bt[(n0 + r) * 768 + k0 + scol];
            }
        }
        for (int ks = 0; ks < 2; ++ks) {
            bf16x8 a[4], b[4];
            for (int i = 0; i < 4; ++i)
                a[i] = *(const bf16x8*)&As[cur][(wm + i * 16 + ln) * 72 + ks * 32 + quad * 8];
            for (int j = 0; j < 4; ++j)
                b[j] = *(const bf16x8*)&Bs[cur][(wn + j * 16 + ln) * 72 + ks * 32 + quad * 8];
            for (int i = 0; i < 4; ++i)
                for (int j = 0; j < 4; ++j)
                    acc[i][j] = __builtin_amdgcn_mfma_f32_16x16x32_bf16(a[i], b[j], acc[i][j], 0, 0, 0);
        }
        if (kt < 11) {
            int nxt = cur ^ 1;
            for (int p = 0; p < 4; ++p) {
                int r = p * 32 + srow;
                *(uint4*)&As[nxt][r * 72 + scol] = ar[p];
                *(uint4*)&Bs[nxt][r * 72 + scol] = br[p];
            }
        }
        __syncthreads();
    }

    const float QSCALE = 0.125f * 1.44269504088896f;  // fold softmax scale * log2(e)
    for (int i = 0; i < 4; ++i) {
        for (int j = 0; j < 4; ++j) {
            int gn = n0 + wn + j * 16 + ln;   // 0..767
            float bia = bias[gn];
            int h = gn >> 6, dd = gn & 63;
            for (int r = 0; r < 4; ++r) {
                int gm = m0 + wm + i * 16 + quad * 4 + r;
                int bb = gm >> 11, ss = gm & 2047;
                float v = acc[i][j][r] + bia;
                if (which == 0) {
                    Qb[((bb * 12 + h) * 2048 + ss) * 64 + dd] = f2bf(v * QSCALE);
                } else if (which == 1) {
                    Kb[((bb * 12 + h) * 2048 + ss) * 64 + dd] = f2bf(v);
                } else {
                    Vtb[((bb * 12 + h) * 64 + dd) * 2048 + ss] = f2bf(v);
                }
            }
        }
    }
}

// ---------------------------------------------------------------- flash attention v6
// R7 dbuf structure + lsum via MFMA-with-ones (no per-iter VALU reductions,
// no final shuffles) + fused exp2->bf16 pack (no fp32 P staging array).
__global__ __launch_bounds__(256) void attn_kernel(
    const ushort_t* __restrict__ Qb, const ushort_t* __restrict__ Kb,
    const ushort_t* __restrict__ Vtb, ushort_t* __restrict__ Ob) {
    __shared__ ushort_t Ks[2][64 * 72];
    __shared__ ushort_t Vs[2][64 * 72];
    int tid = threadIdx.x;
    int qt = blockIdx.x;   // 0..15
    int bh = blockIdx.y;   // 0..47
    int wave = tid >> 6;   // 0..3
    int ln = tid & 15;
    int quad = (tid >> 4) & 3;
    int q0 = qt * 128 + wave * 32;   // this wave's 32 q-columns

    const ushort_t* Qp = Qb + (size_t)bh * 2048 * 64;
    const ushort_t* Kp = Kb + (size_t)bh * 2048 * 64;
    const ushort_t* Vp = Vtb + (size_t)bh * 64 * 2048;

    // Q B-fragments (loop-invariant)
    bf16x8 bqf[2][2];
    for (int g = 0; g < 2; ++g)
        for (int ks = 0; ks < 2; ++ks)
            bqf[g][ks] = *(const bf16x8*)&Qp[(q0 + g * 16 + ln) * 64 + ks * 32 + quad * 8];

    // all-ones A-fragment for column-sum MFMA
    bf16x8 ones;
    for (int j = 0; j < 8; ++j) ones[j] = (__bf16)1.0f;

    // staging indices
    int srow = tid >> 3;            // 0..31 (K rows / V d-rows)
    int c8 = tid & 7;               // 16B chunk within 64 keys
    int scol = c8 * 8;
    int u = c8 & 3;
    int vcol = (c8 >> 2) * 32 + (u & 1) * 16 + (u >> 1) * 4;   // sigma-permuted base

    uint4 kreg[2], vreg[2];

    // prologue: panel 0
    for (int p = 0; p < 2; ++p) {
        kreg[p] = *(const uint4*)&Kp[(p * 32 + srow) * 64 + scol];
        vreg[p] = *(const uint4*)&Vp[(p * 32 + srow) * 2048 + scol];
    }
    for (int p = 0; p < 2; ++p) {
        *(uint4*)&Ks[0][(p * 32 + srow) * 72 + scol] = kreg[p];
        ushort_t* vb = &Vs[0][(p * 32 + srow) * 72 + vcol];
        *(uint2*)vb = make_uint2(vreg[p].x, vreg[p].y);
        *(uint2*)(vb + 8) = make_uint2(vreg[p].z, vreg[p].w);
    }
    __syncthreads();

    floatx4 o_acc[2][4];
    floatx4 acc_l[2];
    floatx4 z = {0.f, 0.f, 0.f, 0.f};
    for (int g = 0; g < 2; ++g) {
        acc_l[g] = z;
        for (int m4 = 0; m4 < 4; ++m4) o_acc[g][m4] = z;
    }

    for (int kt = 0; kt < 32; ++kt) {
        int cur = kt & 1;
        if (kt < 31) {
            for (int p = 0; p < 2; ++p) {
                kreg[p] = *(const uint4*)&Kp[((kt + 1) * 64 + p * 32 + srow) * 64 + scol];
                vreg[p] = *(const uint4*)&Vp[(p * 32 + srow) * 2048 + (kt + 1) * 64 + scol];
            }
        }

        const ushort_t* KsH = Ks[cur];
        const ushort_t* VsH = Vs[cur];

        // K A-frags
        bf16x8 ak[4][2];
        for (int m4 = 0; m4 < 4; ++m4)
            for (int ks = 0; ks < 2; ++ks)
                ak[m4][ks] = *(const bf16x8*)&KsH[(m4 * 16 + ln) * 72 + ks * 32 + quad * 8];

        // S^T = K Q^T
        floatx4 st[2][4];
        for (int g = 0; g < 2; ++g)
            for (int m4 = 0; m4 < 4; ++m4) {
                floatx4 s = z;
                s = __builtin_amdgcn_mfma_f32_16x16x32_bf16(ak[m4][0], bqf[g][0], s, 0, 0, 0);
                s = __builtin_amdgcn_mfma_f32_16x16x32_bf16(ak[m4][1], bqf[g][1], s, 0, 0, 0);
                st[g][m4] = s;
            }

        // V^T A-frags (pre-permuted, contiguous b128)
        bf16x8 av[4][2];
        for (int m4 = 0; m4 < 4; ++m4)
            for (int c = 0; c < 2; ++c)
                av[m4][c] = *(const bf16x8*)&VsH[(m4 * 16 + ln) * 72 + c * 32 + quad * 8];

        // P^T = 2^(S^T) packed straight into B-frags (sigma order);
        // O^T += V^T P^T ; column sums via ones-MFMA
        for (int g = 0; g < 2; ++g) {
            bf16x8 bp[2];
            for (int c = 0; c < 2; ++c) {
                bf16x8 b;
                for (int j = 0; j < 8; ++j) {
                    int m4 = 2 * c + (j >> 2);
                    int r = j & 3;
                    b[j] = (__bf16)__builtin_amdgcn_exp2f(st[g][m4][r]);
                }
                bp[c] = b;
            }
            for (int m4 = 0; m4 < 4; ++m4)
                for (int c = 0; c < 2; ++c)
                    o_acc[g][m4] = __builtin_amdgcn_mfma_f32_16x16x32_bf16(av[m4][c], bp[c], o_acc[g][m4], 0, 0, 0);
            for (int c = 0; c < 2; ++c)
                acc_l[g] = __builtin_amdgcn_mfma_f32_16x16x32_bf16(ones, bp[c], acc_l[g], 0, 0, 0);
        }

        // write prefetched panel into the other buffer
        if (kt < 31) {
            int nxt = cur ^ 1;
            for (int p = 0; p < 2; ++p) {
                *(uint4*)&Ks[nxt][(p * 32 + srow) * 72 + scol] = kreg[p];
                ushort_t* vb = &Vs[nxt][(p * 32 + srow) * 72 + vcol];
                *(uint2*)vb = make_uint2(vreg[p].x, vreg[p].y);
                *(uint2*)(vb + 8) = make_uint2(vreg[p].z, vreg[p].w);
            }
        }
        __syncthreads();
    }

    int b = bh / 12, h = bh % 12;
    for (int g = 0; g < 2; ++g) {
        float inv = 1.f / acc_l[g][0];   // all 16 rows of ones-MFMA result are equal
        int token = b * 2048 + q0 + g * 16 + ln;
        for (int m4 = 0; m4 < 4; ++m4)
            for (int r = 0; r < 4; ++r)
                Ob[token * 768 + h * 64 + m4 * 16 + quad * 4 + r] = f2bf(o_acc[g][m4][r] * inv);
    }
}

// ---------------------------------------------------------------- output projection (fp32 out, dbuf reg-prefetch)
__global__ __launch_bounds__(256) void gemm_out(
    const ushort_t* __restrict__ A, const ushort_t* __restrict__ Bt,
    const float* __restrict__ bias, float* __restrict__ out) {
    __shared__ ushort_t As[2][128 * 72];
    __shared__ ushort_t Bs[2][128 * 72];
    int tid = threadIdx.x;
    int m0 = blockIdx.x * 128;
    int n0 = blockIdx.y * 128;

    int wave = tid >> 6;
    int ln = tid & 15;
    int quad = (tid >> 4) & 3;
    int wm = (wave & 1) * 64;
    int wn = (wave >> 1) * 64;

    floatx4 acc[4][4];
    floatx4 z = {0.f, 0.f, 0.f, 0.f};
    for (int i = 0; i < 4; ++i)
        for (int j = 0; j < 4; ++j) acc[i][j] = z;

    int srow = tid >> 3;
    int scol = (tid & 7) * 8;

    uint4 ar[4], br[4];
    for (int p = 0; p < 4; ++p) {
        int r = p * 32 + srow;
        ar[p] = *(const uint4*)&A[(m0 + r) * 768 + scol];
        br[p] = *(const uint4*)&Bt[(n0 + r) * 768 + scol];
    }
    for (int p = 0; p < 4; ++p) {
        int r = p * 32 + srow;
        *(uint4*)&As[0][r * 72 + scol] = ar[p];
        *(uint4*)&Bs[0][r * 72 + scol] = br[p];
    }
    __syncthreads();

    for (int kt = 0; kt < 12; ++kt) {
        int cur = kt & 1;
        if (kt < 11) {
            int k0 = (kt + 1) * 64;
            for (int p = 0; p < 4; ++p) {
                int r = p * 32 + srow;
                ar[p] = *(const uint4*)&A[(m0 + r) * 768 + k0 + scol];
                br[p] = *(const uint4*)&Bt[(n0 + r) * 768 + k0 + scol];
            }
        }
        for (int ks = 0; ks < 2; ++ks) {
            bf16x8 a[4], b[4];
            for (int i = 0; i < 4; ++i)
                a[i] = *(const bf16x8*)&As[cur][(wm + i * 16 + ln) * 72 + ks * 32 + quad * 8];
            for (int j = 0; j < 4; ++j)
                b[j] = *(const bf16x8*)&Bs[cur][(wn + j * 16 + ln) * 72 + ks * 32 + quad * 8];
            for (int i = 0; i < 4; ++i)
                for (int j = 0; j < 4; ++j)
                    acc[i][j] = __builtin_amdgcn_mfma_f32_16x16x32_bf16(a[i], b[j], acc[i][j], 0, 0, 0);
        }
        if (kt < 11) {
            int nxt = cur ^ 1;
            for (int p = 0; p < 4; ++p) {
                int r = p * 32 + srow;
                *(uint4*)&As[nxt][r * 72 + scol] = ar[p];
                *(uint4*)&Bs[nxt][r * 72 + scol] = br[p];
            }
        }
        __syncthreads();
    }

    for (int i = 0; i < 4; ++i) {
        for (int j = 0; j < 4; ++j) {
            int gn = n0 + wn + j * 16 + ln;
            float bia = bias[gn];
            for (int r = 0; r < 4; ++r) {
                int gm = m0 + wm + i * 16 + quad * 4 + r;
                out[gm * 768 + gn] = acc[i][j][r] + bia;
            }
        }
    }
}

extern "C" void kernel_launch(void* const* d_in, const int* in_sizes, int n_in,
                              void* d_out, int out_size, void* d_ws, size_t ws_size,
                              hipStream_t stream) {
    const float* x  = (const float*)d_in[0];
    const float* Wq = (const float*)d_in[1];
    const float* bq = (const float*)d_in[2];
    const float* Wk = (const float*)d_in[3];
    const float* bk = (const float*)d_in[4];
    const float* Wv = (const float*)d_in[5];
    const float* bv = (const float*)d_in[6];
    const float* Wo = (const float*)d_in[7];
    const float* bo = (const float*)d_in[8];

    const int NTOK = 4 * 2048;        // 8192
    const int NELT = NTOK * 768;      // 6291456
    const int WELT = 768 * 768;       // 589824

    ushort_t* xbf = (ushort_t*)d_ws;
    ushort_t* Tq  = xbf + NELT;
    ushort_t* Tk  = Tq + WELT;
    ushort_t* Tv  = Tk + WELT;
    ushort_t* To  = Tv + WELT;
    ushort_t* Qb  = To + WELT;
    ushort_t* Kb  = Qb + NELT;
    ushort_t* Vtb = Kb + NELT;
    ushort_t* Ob  = Vtb + NELT;

    prep_kernel<<<8448, 256, 0, stream>>>(x, xbf, Wq, Wk, Wv, Wo, Tq, Tk, Tv, To);
    gemm_qkv<<<dim3(64, 18), 256, 0, stream>>>(xbf, Tq, Tk, Tv, bq, bk, bv, Qb, Kb, Vtb);
    attn_kernel<<<dim3(16, 48), 256, 0, stream>>>(Qb, Kb, Vtb, Ob);
    gemm_out<<<dim3(64, 6), 256, 0, stream>>>(Ob, To, bo, (float*)d_out);
}